// Round 12
// baseline (222.307 us; speedup 1.0000x reference)
//
#include <hip/hip_runtime.h>
#include <hip/hip_fp16.h>

typedef __attribute__((ext_vector_type(4))) float f32x4;

#define NROWS 8192
#define DCOLS 256
#define MARGIN 0.5f
#define NT 64          // 8192/128 tiles per dim
#define NBLOCKS 544    // sum over rows bi of ceil((64-bi)/4) runs of <=4 j-tiles

// --- Kernel 1: L2-normalize rows fp32 -> fp8 e5m2 (= truncated fp16), row-major.
__global__ __launch_bounds__(256) void norm_kernel(const float* __restrict__ x,
                                                   unsigned char* __restrict__ e) {
    const int t = threadIdx.x;
    const int l = t & 63;
    const int c = l & 31;
    const int row = blockIdx.x * 8 + (t >> 6) * 2 + (l >> 5);

    const float4 v0 = *reinterpret_cast<const float4*>(&x[row * DCOLS + c * 8]);
    const float4 v1 = *reinterpret_cast<const float4*>(&x[row * DCOLS + c * 8 + 4]);
    float ss = v0.x * v0.x + v0.y * v0.y + v0.z * v0.z + v0.w * v0.w
             + v1.x * v1.x + v1.y * v1.y + v1.z * v1.z + v1.w * v1.w;
#pragma unroll
    for (int off = 16; off >= 1; off >>= 1) ss += __shfl_xor(ss, off, 32);
    const float inv = 1.0f / fmaxf(sqrtf(ss), 1e-12f);

    const float f[8] = {v0.x, v0.y, v0.z, v0.w, v1.x, v1.y, v1.z, v1.w};
    unsigned int lo = 0, hi = 0;
#pragma unroll
    for (int i = 0; i < 4; ++i) {
        const unsigned short hb = __half_as_ushort(__float2half(f[i] * inv));
        lo |= (unsigned int)(hb >> 8) << (8 * i);           // e5m2 = fp16 top byte
    }
#pragma unroll
    for (int i = 0; i < 4; ++i) {
        const unsigned short hb = __half_as_ushort(__float2half(f[4 + i] * inv));
        hi |= (unsigned int)(hb >> 8) << (8 * i);
    }
    uint2 o; o.x = lo; o.y = hi;
    *reinterpret_cast<uint2*>(e + (size_t)row * DCOLS + c * 8) = o;
}

// Stage one 128x32 fp8 B panel (4 KB) with threads 0..255 (waves 0..3).
// Blob layout: blob[g] (16-row group, 0..7) = 512 B; chunk cc = (row cc>>1,
// k-half cc&1). Lane (lr,hk) reads b64 at blob + lr*32 + hk*8.
// Linear LDS dest = base + tid*16 (rule #21).
__device__ __forceinline__ void stage_B(const unsigned char* __restrict__ ebase,
                                        char* Bbuf, int kt, int tid) {
    const int g  = tid >> 5;
    const int cc = tid & 31;
    const int go = (g * 16 + (cc >> 1)) * DCOLS + kt * 32 + (cc & 1) * 16;
    __builtin_amdgcn_global_load_lds(
        (const __attribute__((address_space(1))) void*)(ebase + go),
        (__attribute__((address_space(3))) void*)(Bbuf + tid * 16), 16, 0, 0);
}

// --- Shared core: persistent run-blocks, A-in-registers. Block = (bi, run of
// <=4 j-tiles). 8 waves (4M x 2N), wave tile 32x64, acc[2][4] 16x16x32 bf8_bf8.
// A (128 x K=256 fp8) staged once -> af[8][2] regs. B panels: ring-8.
// STAGE_LOOP=true: counted vmcnt(6) stream (real). STAGE_LOOP=false: all 8
// slots pre-staged, steady-state loop has NO loads / NO vmcnt (probe A/B).
// REP inflates duration for rocprof visibility; `local` accumulates across
// reps (REP=1 for the real kernel -> exact; probes write dead scratch).
template <int REP, bool STAGE_LOOP>
__device__ __forceinline__ void tile_core(const unsigned char* __restrict__ e,
                                          float* __restrict__ outp) {
    const int orig = blockIdx.x;
    int bb = (orig & 7) * 68 + (orig >> 3);
    int bi = 0;
    while (bb >= ((NT - bi) + 3) >> 2) { bb -= ((NT - bi) + 3) >> 2; ++bi; }
    const int j0 = bi + bb * 4;
    const int nj = min(4, NT - j0);
    const int NS = nj * 8;

    __shared__ char As[32768];                // A: [kt 0..7][g 0..7][512 B]
    __shared__ char Bring[8][4096];           // B ring-8
    __shared__ float red[8];

    const int t = threadIdx.x;
    const int l = t & 63;
    const int w = t >> 6;       // 0..7
    const int wm = w >> 1;      // 0..3: rows wm*32
    const int wn = w & 1;       // 0..1: cols wn*64
    const int lr = l & 15;
    const int hk = l >> 4;
    const int lane_off = lr * 32 + hk * 8;
    const bool producer = (w < 4);

    const unsigned char* eA = e + (size_t)bi * 128 * DCOLS;
    float local = 0.0f;

    for (int rep = 0; rep < REP; ++rep) {
        // --- prologue: stage full-K A (4 loads/thread, 512 threads) ---
#pragma unroll
        for (int i = 0; i < 4; ++i) {
            const int u  = i * 512 + t;       // 0..2047
            const int kt = u >> 8, g = (u >> 5) & 7, cc = u & 31;
            const int go = (g * 16 + (cc >> 1)) * DCOLS + kt * 32 + (cc & 1) * 16;
            __builtin_amdgcn_global_load_lds(
                (const __attribute__((address_space(1))) void*)(eA + go),
                (__attribute__((address_space(3))) void*)(As + u * 16), 16, 0, 0);
        }
        if (producer) {
            if (STAGE_LOOP) {
#pragma unroll
                for (int p = 0; p < 7; ++p)   // slots 0..6 (panel j0, kt 0..6)
                    stage_B(e + (size_t)(j0 + (p >> 3)) * 128 * DCOLS, Bring[p], p & 7, t);
            } else {
#pragma unroll
                for (int p = 0; p < 8; ++p)   // ALL slots: loop needs no loads
                    stage_B(e + (size_t)j0 * 128 * DCOLS, Bring[p], p, t);
            }
        }
        // A-visibility gate. STAGE_LOOP: producers keep their 7 B loads in
        // flight (vmcnt(7) retires leftovers+A, in-order); else full drain.
        if (STAGE_LOOP && producer) asm volatile("s_waitcnt vmcnt(7)" ::: "memory");
        else                        asm volatile("s_waitcnt vmcnt(0)" ::: "memory");
        __builtin_amdgcn_s_barrier();
        __builtin_amdgcn_sched_barrier(0);

        // --- hoist A fragments to registers (LDS As then dead) ---
        long af[8][2];
#pragma unroll
        for (int kt = 0; kt < 8; ++kt)
#pragma unroll
            for (int m = 0; m < 2; ++m)
                af[kt][m] = *reinterpret_cast<const long*>(
                    As + kt * 4096 + (wm * 2 + m) * 512 + lane_off);

        f32x4 acc[2][4];
#pragma unroll
        for (int m = 0; m < 2; ++m)
#pragma unroll
            for (int n = 0; n < 4; ++n)
                acc[m][n] = (f32x4){0.f, 0.f, 0.f, 0.f};

        for (int jx = 0; jx < nj; ++jx) {
            const int jt = j0 + jx;
#pragma unroll
            for (int kt = 0; kt < 8; ++kt) {
                if (STAGE_LOOP && producer)
                    asm volatile("s_waitcnt vmcnt(6)" ::: "memory");
                __builtin_amdgcn_s_barrier();
                __builtin_amdgcn_sched_barrier(0);
                if (STAGE_LOOP && producer) {
                    int s7 = jx * 8 + kt + 7;
                    if (s7 >= NS) s7 -= NS;   // wrap: rewrites retired slots with
                                              // identical bytes (benign, determ.)
                    stage_B(e + (size_t)(j0 + (s7 >> 3)) * 128 * DCOLS,
                            Bring[(kt + 7) & 7], s7 & 7, t);
                }
                long bf[4];
#pragma unroll
                for (int n = 0; n < 4; ++n)
                    bf[n] = *reinterpret_cast<const long*>(
                        Bring[kt] + (wn * 4 + n) * 512 + lane_off);
                __builtin_amdgcn_s_setprio(1);
#pragma unroll
                for (int m = 0; m < 2; ++m)
#pragma unroll
                    for (int n = 0; n < 4; ++n)
                        acc[m][n] = __builtin_amdgcn_mfma_f32_16x16x32_bf8_bf8(
                            af[kt][m], bf[n], acc[m][n], 0, 0, 0);
                __builtin_amdgcn_s_setprio(0);
            }
            // --- tile jt done: fused masked-relu reduce, reset acc ---
            // C/D layout (m89-verified): col=lane&15, row=(lane>>4)*4+reg.
            const int gi0 = bi * 128 + wm * 32;
            const int gj0 = jt * 128 + wn * 64;
            if (jt == bi) {
#pragma unroll
                for (int m = 0; m < 2; ++m)
#pragma unroll
                    for (int n = 0; n < 4; ++n) {
#pragma unroll
                        for (int r = 0; r < 4; ++r) {
                            const int gi = gi0 + m * 16 + hk * 4 + r;
                            const int gj = gj0 + n * 16 + lr;
                            local += (gi < gj) ? fmaxf(acc[m][n][r] - MARGIN, 0.0f) : 0.0f;
                        }
                        acc[m][n] = (f32x4){0.f, 0.f, 0.f, 0.f};
                    }
            } else {
#pragma unroll
                for (int m = 0; m < 2; ++m)
#pragma unroll
                    for (int n = 0; n < 4; ++n) {
#pragma unroll
                        for (int r = 0; r < 4; ++r)
                            local += fmaxf(acc[m][n][r] - MARGIN, 0.0f);
                        acc[m][n] = (f32x4){0.f, 0.f, 0.f, 0.f};
                    }
            }
        }
        // rep boundary: leftover in-flight stages handled by next prologue's
        // vmcnt gate (in-order retirement); identical-byte slot rewrites.
    }

    // --- block reduction -> one partial per block ---
#pragma unroll
    for (int off = 32; off >= 1; off >>= 1) local += __shfl_down(local, off);
    if (l == 0) red[w] = local;
    __syncthreads();
    if (t == 0) {
        float s = 0.0f;
#pragma unroll
        for (int i = 0; i < 8; ++i) s += red[i];
        outp[orig] = s;
    }
}

// Real kernel: REP=1, counted-vmcnt stream, (512,2) -> no VGPR cap pressure.
__global__ __launch_bounds__(512, 2) void tile_kernel(const unsigned char* __restrict__ e,
                                                      float* __restrict__ part) {
    tile_core<1, true>(e, part);
}
// Probe A: real structure x2 (rocprof visibility over the ~42us harness fills).
__global__ __launch_bounds__(512, 2) void probe_full(const unsigned char* __restrict__ e,
                                                     float* __restrict__ scr) {
    tile_core<2, true>(e, scr);
}
// Probe B: no in-loop staging/vmcnt (slots pre-staged), x4.
__global__ __launch_bounds__(512, 2) void probe_nostage(const unsigned char* __restrict__ e,
                                                        float* __restrict__ scr) {
    tile_core<4, false>(e, scr);
}

// --- Kernel 3: reduce NBLOCKS partials, finalize ---
__global__ __launch_bounds__(256) void fin_kernel(const float* __restrict__ part,
                                                  float* __restrict__ out) {
    __shared__ float red[4];
    const int t = threadIdx.x;
    float v = part[t] + part[t + 256] + (t < NBLOCKS - 512 ? part[t + 512] : 0.0f);
#pragma unroll
    for (int off = 32; off >= 1; off >>= 1) v += __shfl_down(v, off);
    if ((t & 63) == 0) red[t >> 6] = v;
    __syncthreads();
    if (t == 0) out[0] = (red[0] + red[1] + red[2] + red[3]) / 33550336.0f;
}

extern "C" void kernel_launch(void* const* d_in, const int* in_sizes, int n_in,
                              void* d_out, int out_size, void* d_ws, size_t ws_size,
                              hipStream_t stream) {
    const float* x = (const float*)d_in[0];
    float* out = (float*)d_out;
    unsigned char* e = (unsigned char*)d_ws;                        // 2 MB fp8
    float* part = (float*)((char*)d_ws + (size_t)NROWS * DCOLS);    // 544 floats
    float* scr1 = (float*)((char*)d_ws + (16u << 20));              // dead probe out
    float* scr2 = (float*)((char*)d_ws + (20u << 20));              // dead probe out

    norm_kernel<<<NROWS / 8, 256, 0, stream>>>(x, e);
    tile_kernel<<<NBLOCKS, 512, 0, stream>>>(e, part);
    fin_kernel<<<1, 256, 0, stream>>>(part, out);
    // diagnostics (dead outputs, after the result path)
    probe_full<<<NBLOCKS, 512, 0, stream>>>(e, scr1);
    probe_nostage<<<NBLOCKS, 512, 0, stream>>>(e, scr2);
}

// Round 13
// 37.511 us; speedup vs baseline: 5.9264x; 5.9264x over previous
//
#include <hip/hip_runtime.h>
#include <hip/hip_fp16.h>

typedef __attribute__((ext_vector_type(4))) float f32x4;

#define NROWS 8192
#define DCOLS 256
#define MARGIN 0.5f
#define NT 64          // 8192/128 tiles per dim
#define NBLOCKS 544    // sum over rows bi of ceil((64-bi)/4) runs of <=4 j-tiles

// --- Kernel 1: L2-normalize rows fp32 -> fp8 e5m2 (= truncated fp16), row-major.
__global__ __launch_bounds__(256) void norm_kernel(const float* __restrict__ x,
                                                   unsigned char* __restrict__ e) {
    const int t = threadIdx.x;
    const int l = t & 63;
    const int c = l & 31;
    const int row = blockIdx.x * 8 + (t >> 6) * 2 + (l >> 5);

    const float4 v0 = *reinterpret_cast<const float4*>(&x[row * DCOLS + c * 8]);
    const float4 v1 = *reinterpret_cast<const float4*>(&x[row * DCOLS + c * 8 + 4]);
    float ss = v0.x * v0.x + v0.y * v0.y + v0.z * v0.z + v0.w * v0.w
             + v1.x * v1.x + v1.y * v1.y + v1.z * v1.z + v1.w * v1.w;
#pragma unroll
    for (int off = 16; off >= 1; off >>= 1) ss += __shfl_xor(ss, off, 32);
    const float inv = 1.0f / fmaxf(sqrtf(ss), 1e-12f);

    const float f[8] = {v0.x, v0.y, v0.z, v0.w, v1.x, v1.y, v1.z, v1.w};
    unsigned int lo = 0, hi = 0;
#pragma unroll
    for (int i = 0; i < 4; ++i) {
        const unsigned short hb = __half_as_ushort(__float2half(f[i] * inv));
        lo |= (unsigned int)(hb >> 8) << (8 * i);           // e5m2 = fp16 top byte
    }
#pragma unroll
    for (int i = 0; i < 4; ++i) {
        const unsigned short hb = __half_as_ushort(__float2half(f[4 + i] * inv));
        hi |= (unsigned int)(hb >> 8) << (8 * i);
    }
    uint2 o; o.x = lo; o.y = hi;
    *reinterpret_cast<uint2*>(e + (size_t)row * DCOLS + c * 8) = o;
}

// Stage one 128x32 fp8 B panel (4 KB) with threads 0..255 (waves 0..3).
// CONFLICT-FREE blob layout (R12 fix): blob[g] (16-row group) = 512 B;
// chunk (row lr, k-half c) at byte c*256 + lr*16  (16B contiguous from global:
// row g*16+lr, bytes kt*32+c*16..+16). Lane (lr,hk) reads b64 at
// (hk>>1)*256 + lr*16 + (hk&1)*8 -> 16-lane phases hit banks {0,4,..,28} at
// 2 lanes/bank = free (m136). Linear LDS dest = base + tid*16 (rule #21).
__device__ __forceinline__ void stage_B(const unsigned char* __restrict__ ebase,
                                        char* Bbuf, int kt, int tid) {
    const int g  = tid >> 5;
    const int cc = tid & 31;                  // cc = c*16 + lr
    const int go = (g * 16 + (cc & 15)) * DCOLS + kt * 32 + (cc >> 4) * 16;
    __builtin_amdgcn_global_load_lds(
        (const __attribute__((address_space(1))) void*)(ebase + go),
        (__attribute__((address_space(3))) void*)(Bbuf + tid * 16), 16, 0, 0);
}

// --- Kernel 2: persistent run-blocks, A-in-registers, conflict-free LDS.
// Block = (bi, run of <=4 j-tiles). 8 waves (4M x 2N), wave tile 32x64,
// acc[2][4] of 16x16x32 bf8_bf8. A (128 x K=256 fp8) staged once -> af[8][2]
// regs. B panels (4 KB per BK=32 step) stream through ring-8 with counted
// vmcnt(6) (T4): producers (waves 0..3) wait only the oldest load (issued 7
// steps back), never drain. Per step per wave: 4 conflict-free b64 + 8 MFMA.
__global__ __launch_bounds__(512, 2) void tile_kernel(const unsigned char* __restrict__ e,
                                                      float* __restrict__ part) {
    // XCD-chunked bijective remap (544 = 8*68)
    const int orig = blockIdx.x;
    int bb = (orig & 7) * 68 + (orig >> 3);
    int bi = 0;
    while (bb >= ((NT - bi) + 3) >> 2) { bb -= ((NT - bi) + 3) >> 2; ++bi; }
    const int j0 = bi + bb * 4;
    const int nj = min(4, NT - j0);
    const int NS = nj * 8;

    __shared__ char As[32768];                // A: [kt 0..7][g 0..7][512 B]
    __shared__ char Bring[8][4096];           // B ring-8
    __shared__ float red[8];

    const int t = threadIdx.x;
    const int l = t & 63;
    const int w = t >> 6;       // 0..7
    const int wm = w >> 1;      // 0..3: rows wm*32
    const int wn = w & 1;       // 0..1: cols wn*64
    const int lr = l & 15;
    const int hk = l >> 4;
    const int lane_off = (hk >> 1) * 256 + lr * 16 + (hk & 1) * 8;  // conflict-free
    const bool producer = (w < 4);

    const unsigned char* eA = e + (size_t)bi * 128 * DCOLS;

    // --- prologue: stage full-K A (4 loads/thread, 512 threads) ---
#pragma unroll
    for (int i = 0; i < 4; ++i) {
        const int u  = i * 512 + t;           // 0..2047 = kt*256 + g*32 + cc
        const int kt = u >> 8, g = (u >> 5) & 7, cc = u & 31;
        const int go = (g * 16 + (cc & 15)) * DCOLS + kt * 32 + (cc >> 4) * 16;
        __builtin_amdgcn_global_load_lds(
            (const __attribute__((address_space(1))) void*)(eA + go),
            (__attribute__((address_space(3))) void*)(As + u * 16), 16, 0, 0);
    }
    // B panels 0..6 staged by waves 0..3
    if (producer) {
#pragma unroll
        for (int p = 0; p < 7; ++p)   // p < 7 <= NS always
            stage_B(e + (size_t)(j0 + (p >> 3)) * 128 * DCOLS, Bring[p], p & 7, t);
    }
    // A visibility: producers keep their 7 B loads in flight; consumers drain.
    if (producer) asm volatile("s_waitcnt vmcnt(7)" ::: "memory");
    else          asm volatile("s_waitcnt vmcnt(0)" ::: "memory");
    __builtin_amdgcn_s_barrier();
    __builtin_amdgcn_sched_barrier(0);

    // --- hoist A fragments to registers (one-time; LDS As then dead) ---
    long af[8][2];
#pragma unroll
    for (int kt = 0; kt < 8; ++kt)
#pragma unroll
        for (int m = 0; m < 2; ++m)
            af[kt][m] = *reinterpret_cast<const long*>(
                As + kt * 4096 + (wm * 2 + m) * 512 + lane_off);

    f32x4 acc[2][4];
#pragma unroll
    for (int m = 0; m < 2; ++m)
#pragma unroll
        for (int n = 0; n < 4; ++n)
            acc[m][n] = (f32x4){0.f, 0.f, 0.f, 0.f};

    float local = 0.0f;
    for (int jx = 0; jx < nj; ++jx) {
        const int jt = j0 + jx;
#pragma unroll
        for (int kt = 0; kt < 8; ++kt) {
            // gate slot kt: producer's oldest outstanding load IS slot kt
            if (producer) asm volatile("s_waitcnt vmcnt(6)" ::: "memory");
            __builtin_amdgcn_s_barrier();
            __builtin_amdgcn_sched_barrier(0);
            // stage step s+7 into slot (kt+7)&7 (read-complete at step s-1;
            // wrap-stages rewrite retired slots with identical bytes - benign)
            if (producer) {
                int s7 = jx * 8 + kt + 7;
                if (s7 >= NS) s7 -= NS;
                stage_B(e + (size_t)(j0 + (s7 >> 3)) * 128 * DCOLS,
                        Bring[(kt + 7) & 7], s7 & 7, t);
            }
            long bf[4];
#pragma unroll
            for (int n = 0; n < 4; ++n)
                bf[n] = *reinterpret_cast<const long*>(
                    Bring[kt] + (wn * 4 + n) * 512 + lane_off);
            __builtin_amdgcn_s_setprio(1);
#pragma unroll
            for (int m = 0; m < 2; ++m)
#pragma unroll
                for (int n = 0; n < 4; ++n)
                    acc[m][n] = __builtin_amdgcn_mfma_f32_16x16x32_bf8_bf8(
                        af[kt][m], bf[n], acc[m][n], 0, 0, 0);
            __builtin_amdgcn_s_setprio(0);
        }
        // --- tile jt complete: fused masked-relu reduce, reset acc ---
        // C/D layout (m89-verified, dtype-independent): col=lane&15,
        // row=(lane>>4)*4+reg.
        const int gi0 = bi * 128 + wm * 32;
        const int gj0 = jt * 128 + wn * 64;
        if (jt == bi) {
#pragma unroll
            for (int m = 0; m < 2; ++m)
#pragma unroll
                for (int n = 0; n < 4; ++n) {
#pragma unroll
                    for (int r = 0; r < 4; ++r) {
                        const int gi = gi0 + m * 16 + hk * 4 + r;
                        const int gj = gj0 + n * 16 + lr;
                        local += (gi < gj) ? fmaxf(acc[m][n][r] - MARGIN, 0.0f) : 0.0f;
                    }
                    acc[m][n] = (f32x4){0.f, 0.f, 0.f, 0.f};
                }
        } else {   // jt > bi: all pairs strictly upper-triangular
#pragma unroll
            for (int m = 0; m < 2; ++m)
#pragma unroll
                for (int n = 0; n < 4; ++n) {
#pragma unroll
                    for (int r = 0; r < 4; ++r)
                        local += fmaxf(acc[m][n][r] - MARGIN, 0.0f);
                    acc[m][n] = (f32x4){0.f, 0.f, 0.f, 0.f};
                }
        }
    }

    // --- block reduction -> one partial per block, no atomics ---
#pragma unroll
    for (int off = 32; off >= 1; off >>= 1) local += __shfl_down(local, off);
    if (l == 0) red[w] = local;
    __syncthreads();
    if (t == 0) {
        float s = 0.0f;
#pragma unroll
        for (int i = 0; i < 8; ++i) s += red[i];
        part[orig] = s;
    }
}

// --- Kernel 3: reduce NBLOCKS partials, finalize ---
__global__ __launch_bounds__(256) void fin_kernel(const float* __restrict__ part,
                                                  float* __restrict__ out) {
    __shared__ float red[4];
    const int t = threadIdx.x;
    float v = part[t] + part[t + 256] + (t < NBLOCKS - 512 ? part[t + 512] : 0.0f);
#pragma unroll
    for (int off = 32; off >= 1; off >>= 1) v += __shfl_down(v, off);
    if ((t & 63) == 0) red[t >> 6] = v;
    __syncthreads();
    if (t == 0) out[0] = (red[0] + red[1] + red[2] + red[3]) / 33550336.0f;
}

extern "C" void kernel_launch(void* const* d_in, const int* in_sizes, int n_in,
                              void* d_out, int out_size, void* d_ws, size_t ws_size,
                              hipStream_t stream) {
    const float* x = (const float*)d_in[0];
    float* out = (float*)d_out;
    unsigned char* e = (unsigned char*)d_ws;                        // 2 MB fp8
    float* part = (float*)((char*)d_ws + (size_t)NROWS * DCOLS);    // 544 floats

    norm_kernel<<<NROWS / 8, 256, 0, stream>>>(x, e);
    tile_kernel<<<NBLOCKS, 512, 0, stream>>>(e, part);
    fin_kernel<<<1, 256, 0, stream>>>(part, out);
}

// Round 14
// 33.190 us; speedup vs baseline: 6.6979x; 1.1302x over previous
//
#include <hip/hip_runtime.h>
#include <hip/hip_fp16.h>

typedef __attribute__((ext_vector_type(4))) float f32x4;

#define NROWS 8192
#define DCOLS 256
#define MARGIN 0.5f
#define NT 64          // 8192/128 tiles per dim
#define NBLOCKS 544    // sum over rows bi of ceil((64-bi)/4) runs of <=4 j-tiles

// --- Kernel 1: L2-normalize rows fp32 -> fp8 e5m2 (= truncated fp16), row-major.
__global__ __launch_bounds__(256) void norm_kernel(const float* __restrict__ x,
                                                   unsigned char* __restrict__ e) {
    const int t = threadIdx.x;
    const int l = t & 63;
    const int c = l & 31;
    const int row = blockIdx.x * 8 + (t >> 6) * 2 + (l >> 5);

    const float4 v0 = *reinterpret_cast<const float4*>(&x[row * DCOLS + c * 8]);
    const float4 v1 = *reinterpret_cast<const float4*>(&x[row * DCOLS + c * 8 + 4]);
    float ss = v0.x * v0.x + v0.y * v0.y + v0.z * v0.z + v0.w * v0.w
             + v1.x * v1.x + v1.y * v1.y + v1.z * v1.z + v1.w * v1.w;
#pragma unroll
    for (int off = 16; off >= 1; off >>= 1) ss += __shfl_xor(ss, off, 32);
    const float inv = 1.0f / fmaxf(sqrtf(ss), 1e-12f);

    const float f[8] = {v0.x, v0.y, v0.z, v0.w, v1.x, v1.y, v1.z, v1.w};
    unsigned int lo = 0, hi = 0;
#pragma unroll
    for (int i = 0; i < 4; ++i) {
        const unsigned short hb = __half_as_ushort(__float2half(f[i] * inv));
        lo |= (unsigned int)(hb >> 8) << (8 * i);           // e5m2 = fp16 top byte
    }
#pragma unroll
    for (int i = 0; i < 4; ++i) {
        const unsigned short hb = __half_as_ushort(__float2half(f[4 + i] * inv));
        hi |= (unsigned int)(hb >> 8) << (8 * i);
    }
    uint2 o; o.x = lo; o.y = hi;
    *reinterpret_cast<uint2*>(e + (size_t)row * DCOLS + c * 8) = o;
}

// --- Kernel 2: BARRIER-FREE wave-private pipeline.
// Block = (bi, run of <=4 j-tiles), 256 threads = 4 free-drifting waves.
// Tile 128x128; wave wn owns cols wn*32 (acc[8][2] of 16x16x32 bf8_bf8).
// A (128 x K=256 fp8, 32 KB, k-major conflict-free layout) staged once by all;
// ONE barrier after it. B: each wave stages its OWN 1 KB slice (rows wn*32..+31
// of each K-step panel) into a wave-private ring-4 -> slot reuse + visibility
// ordered by the wave's own vmcnt; NO in-loop barriers, no producer/consumer.
// LDS layouts: 16B-stride k-major (2 lanes/bank per 16-lane phase = free, m136).
__global__ __launch_bounds__(256, 3) void tile_kernel(const unsigned char* __restrict__ e,
                                                      float* __restrict__ part) {
    // XCD-chunked bijective remap (544 = 8*68)
    const int orig = blockIdx.x;
    int bb = (orig & 7) * 68 + (orig >> 3);
    int bi = 0;
    while (bb >= ((NT - bi) + 3) >> 2) { bb -= ((NT - bi) + 3) >> 2; ++bi; }
    const int j0 = bi + bb * 4;
    const int nj = min(4, NT - j0);
    const int NS = nj * 8;                    // stream of (jt,kt) steps, mult of 8

    __shared__ char As[32768];                // [kt 0..7][khalf 0..1][row 0..127][16B]
    __shared__ char Bw[4][4][1024];           // [wave][slot][khalf 0..1][row 0..31][16B]
    __shared__ float red[4];

    const int t = threadIdx.x;
    const int l = t & 63;
    const int w = t >> 6;       // wave id = N-slice: cols wn*32
    const int wn = w;
    const int lr = l & 15;
    const int hk = l >> 4;
    // conflict-free read offset within a [khalf][row][16B] region of R rows:
    //   (hk>>1)*R*16 + row*16 + (hk&1)*8
    const unsigned char* eA = e + (size_t)bi * 128 * DCOLS;
    const unsigned char* eB = e + (size_t)j0 * 128 * DCOLS + wn * 32 * DCOLS;
    char* myB = Bw[w][0];

    // --- prologue: stage A (8 loads/thread, 2048 chunks) ---
#pragma unroll
    for (int i = 0; i < 8; ++i) {
        const int u = i * 256 + t;            // kt*256 + khalf*128 + row
        const int kt = u >> 8, khalf = (u >> 7) & 1, row = u & 127;
        __builtin_amdgcn_global_load_lds(
            (const __attribute__((address_space(1))) void*)(eA + row * DCOLS + kt * 32 + khalf * 16),
            (__attribute__((address_space(3))) void*)(As + u * 16), 16, 0, 0);
    }
    // wave-private B slices, streams 0..2 -> slots 0..2 (1 load/lane each):
    // lane l: row_local = l&31, khalf = l>>5; dest chunk = khalf*32+... = l (linear)
#pragma unroll
    for (int p = 0; p < 3; ++p) {
        // stream p: jt = j0 + (p>>3) = j0, kt = p
        __builtin_amdgcn_global_load_lds(
            (const __attribute__((address_space(1))) void*)(eB + (l & 31) * DCOLS + p * 32 + (l >> 5) * 16),
            (__attribute__((address_space(3))) void*)(myB + p * 1024 + l * 16), 16, 0, 0);
    }
    // A's 8 loads are this wave's oldest: vmcnt(3) retires them, keeps 3 B in flight.
    asm volatile("s_waitcnt vmcnt(3)" ::: "memory");
    __builtin_amdgcn_s_barrier();             // the ONLY barrier: publishes A
    __builtin_amdgcn_sched_barrier(0);

    f32x4 acc[8][2];
#pragma unroll
    for (int m = 0; m < 8; ++m)
#pragma unroll
        for (int n = 0; n < 2; ++n)
            acc[m][n] = (f32x4){0.f, 0.f, 0.f, 0.f};

    float local = 0.0f;
    const int rd_base = (hk >> 1) ? 1 : 0;    // khalf of this lane's k-offset
    for (int jx = 0; jx < nj; ++jx) {
        const int jt = j0 + jx;
#pragma unroll
        for (int kt = 0; kt < 8; ++kt) {
            const int s = jx * 8 + kt;
            // own oldest B stage (issued 3 steps back) has landed; 2 stay in flight
            asm volatile("s_waitcnt vmcnt(2)" ::: "memory");
            __builtin_amdgcn_sched_barrier(0);
            // stage stream s+3 into slot (s+3)&3 (= slot read at step s-1: its
            // ds_reads were consumed by step s-1's MFMAs -> in-order safe).
            // Wrap rewrites prologue slots with identical bytes (benign).
            {
                int s3 = s + 3; if (s3 >= NS) s3 -= NS;
                __builtin_amdgcn_global_load_lds(
                    (const __attribute__((address_space(1))) void*)(eB
                        + (size_t)(s3 >> 3) * 128 * DCOLS
                        + (l & 31) * DCOLS + (s3 & 7) * 32 + (l >> 5) * 16),
                    (__attribute__((address_space(3))) void*)(myB + (s3 & 3) * 1024 + l * 16),
                    16, 0, 0);
            }
            // B fragments (own slot, conflict-free)
            long bf[2];
#pragma unroll
            for (int n = 0; n < 2; ++n)
                bf[n] = *reinterpret_cast<const long*>(
                    myB + (s & 3) * 1024 + rd_base * 512 + (n * 16 + lr) * 16 + (hk & 1) * 8);
            // A fragments for this kt (shared LDS, conflict-free)
            long af[8];
#pragma unroll
            for (int m = 0; m < 8; ++m)
                af[m] = *reinterpret_cast<const long*>(
                    As + kt * 4096 + rd_base * 2048 + (m * 16 + lr) * 16 + (hk & 1) * 8);
            __builtin_amdgcn_s_setprio(1);
#pragma unroll
            for (int m = 0; m < 8; ++m)
#pragma unroll
                for (int n = 0; n < 2; ++n)
                    acc[m][n] = __builtin_amdgcn_mfma_f32_16x16x32_bf8_bf8(
                        af[m], bf[n], acc[m][n], 0, 0, 0);
            __builtin_amdgcn_s_setprio(0);
        }
        // --- tile jt complete: fused masked-relu reduce, reset acc ---
        // C/D layout (m89-verified, dtype-independent): col=lane&15,
        // row=(lane>>4)*4+reg.
        const int gi0 = bi * 128;
        const int gj0 = jt * 128 + wn * 32;
        if (jt == bi) {
#pragma unroll
            for (int m = 0; m < 8; ++m)
#pragma unroll
                for (int n = 0; n < 2; ++n) {
#pragma unroll
                    for (int r = 0; r < 4; ++r) {
                        const int gi = gi0 + m * 16 + hk * 4 + r;
                        const int gj = gj0 + n * 16 + lr;
                        local += (gi < gj) ? fmaxf(acc[m][n][r] - MARGIN, 0.0f) : 0.0f;
                    }
                    acc[m][n] = (f32x4){0.f, 0.f, 0.f, 0.f};
                }
        } else {   // jt > bi: all pairs strictly upper-triangular
#pragma unroll
            for (int m = 0; m < 8; ++m)
#pragma unroll
                for (int n = 0; n < 2; ++n) {
#pragma unroll
                    for (int r = 0; r < 4; ++r)
                        local += fmaxf(acc[m][n][r] - MARGIN, 0.0f);
                    acc[m][n] = (f32x4){0.f, 0.f, 0.f, 0.f};
                }
        }
    }

    // --- block reduction -> one partial per block, no atomics ---
#pragma unroll
    for (int off = 32; off >= 1; off >>= 1) local += __shfl_down(local, off);
    if (l == 0) red[w] = local;
    __syncthreads();
    if (t == 0) part[orig] = red[0] + red[1] + red[2] + red[3];
}

// --- Kernel 3: reduce NBLOCKS partials, finalize ---
__global__ __launch_bounds__(256) void fin_kernel(const float* __restrict__ part,
                                                  float* __restrict__ out) {
    __shared__ float red[4];
    const int t = threadIdx.x;
    float v = part[t] + part[t + 256] + (t < NBLOCKS - 512 ? part[t + 512] : 0.0f);
#pragma unroll
    for (int off = 32; off >= 1; off >>= 1) v += __shfl_down(v, off);
    if ((t & 63) == 0) red[t >> 6] = v;
    __syncthreads();
    if (t == 0) out[0] = (red[0] + red[1] + red[2] + red[3]) / 33550336.0f;
}

extern "C" void kernel_launch(void* const* d_in, const int* in_sizes, int n_in,
                              void* d_out, int out_size, void* d_ws, size_t ws_size,
                              hipStream_t stream) {
    const float* x = (const float*)d_in[0];
    float* out = (float*)d_out;
    unsigned char* e = (unsigned char*)d_ws;                        // 2 MB fp8
    float* part = (float*)((char*)d_ws + (size_t)NROWS * DCOLS);    // 544 floats

    norm_kernel<<<NROWS / 8, 256, 0, stream>>>(x, e);
    tile_kernel<<<NBLOCKS, 256, 0, stream>>>(e, part);
    fin_kernel<<<1, 256, 0, stream>>>(part, out);
}